// Round 16
// baseline (247.268 us; speedup 1.0000x reference)
//
#include <hip/hip_runtime.h>
#include <hip/hip_bf16.h>
#include <hip/hip_fp16.h>
#include <math.h>

#define C 128
#define BCAP 12288   // per-bucket staging capacity (expected ~8.2K edges/bucket)

using half8x = __attribute__((ext_vector_type(8))) _Float16;
using half4x = __attribute__((ext_vector_type(4))) _Float16;
using f32x4  = __attribute__((ext_vector_type(4))) float;

__device__ inline float4 h4_to_f4(uint2 u) {
    __half2 p0 = *(__half2*)&u.x;
    __half2 p1 = *(__half2*)&u.y;
    float2 f0 = __half22float2(p0), f1 = __half22float2(p1);
    return make_float4(f0.x, f0.y, f1.x, f1.y);
}

__device__ inline float softplusf(float v) {
    return (v > 20.f) ? v : log1pf(expf(v));
}

// ---------------- init: zero bucket cursors + colsum + pSum ----------------
__global__ __launch_bounds__(256) void initk(unsigned* gcur, float* colsum, float* pSum) {
    int t = threadIdx.x;
    gcur[t] = 0u;
    if (t < 128) colsum[t] = 0.f;
    if (t == 128) pSum[0] = 0.f;
}

// ---------------- transpose weights to fp16 once ----------------
__global__ __launch_bounds__(256) void wtk(const float* __restrict__ aW, const float* __restrict__ cW,
                                           const float* __restrict__ a1W,
                                           __half* __restrict__ wt, __half* __restrict__ a1wt) {
    int idx = blockIdx.x * 256 + threadIdx.x;
    if (idx < 32768) {
        int y = idx >> 14, r = idx & 16383;
        int k = r >> 7, n = r & 127;
        const float* W = y ? cW : aW;
        wt[((size_t)y << 14) + n * 128 + k] = __float2half(W[k * 128 + n]);
    } else if (idx < 36864) {
        int r = idx - 32768;
        int k = r >> 5, n = r & 31;
        a1wt[n * 128 + k] = __float2half(a1W[k * 32 + n]);
    }
}

// ---------------- bucket-bin edges (counting sort level 1) ----------------
__global__ __launch_bounds__(256) void bink(const int* __restrict__ ei,
                                            unsigned* __restrict__ gcur,
                                            unsigned* __restrict__ gstage,
                                            int E, int NBKT) {
    __shared__ unsigned raw[6400];
    __shared__ unsigned image[6400];
    __shared__ unsigned cnt[256];
    __shared__ unsigned pref[256];
    __shared__ unsigned cur[256];
    __shared__ unsigned gb[256];
    int t = threadIdx.x, b = blockIdx.x;
    int elo = (int)((long long)b * E / 256);
    int ehi = (int)((long long)(b + 1) * E / 256);
    int n = ehi - elo;

    for (int i = t; i < n; i += 256) {
        int d = __builtin_nontemporal_load(ei + E + elo + i);
        int s = __builtin_nontemporal_load(ei + elo + i);
        raw[i] = (unsigned)s | ((unsigned)(d & 255) << 16) | ((unsigned)(d >> 8) << 24);
    }
    cnt[t] = 0u; cur[t] = 0u;
    __syncthreads();
    for (int i = t; i < n; i += 256) atomicAdd(&cnt[raw[i] >> 24], 1u);
    __syncthreads();
    pref[t] = cnt[t];
    __syncthreads();
    for (int off = 1; off < 256; off <<= 1) {
        unsigned add = (t >= off) ? pref[t - off] : 0u;
        __syncthreads();
        pref[t] += add;
        __syncthreads();
    }
    gb[t] = (t < NBKT && cnt[t]) ? atomicAdd(&gcur[t], cnt[t]) : 0u;
    __syncthreads();
    for (int i = t; i < n; i += 256) {
        unsigned v = raw[i];
        unsigned B = v >> 24;
        unsigned pos = (pref[B] - cnt[B]) + atomicAdd(&cur[B], 1u);
        image[pos] = v & 0xFFFFFFu;
    }
    __syncthreads();
    int wv = t >> 6, lane = t & 63;
    for (int B = wv; B < NBKT; B += 4) {
        unsigned c = cnt[B];
        if (!c) continue;
        unsigned eb = pref[B] - c;
        unsigned gbase = gb[B];
        unsigned c2 = (gbase < BCAP) ? ((c < BCAP - gbase) ? c : BCAP - gbase) : 0u;
        for (unsigned i = lane; i < c2; i += 64)
            gstage[(size_t)B * BCAP + gbase + i] = image[eb + i];
    }
}

// ---------------- scan bucket totals ----------------
__global__ void bktscank(const unsigned* __restrict__ gcur, unsigned* __restrict__ bktbase, int NBKT) {
    __shared__ unsigned tmp[256];
    int t = threadIdx.x;
    unsigned g = (t < NBKT) ? gcur[t] : 0u;
    unsigned v = (g < BCAP) ? g : BCAP;
    tmp[t] = v;
    __syncthreads();
    for (int off = 1; off < 256; off <<= 1) {
        unsigned add = (t >= off) ? tmp[t - off] : 0u;
        __syncthreads();
        tmp[t] += add;
        __syncthreads();
    }
    if (t < NBKT) bktbase[t] = tmp[t] - v;   // exclusive
}

// ---------------- place (counting sort level 2) ----------------
__global__ __launch_bounds__(256) void placek(const unsigned* __restrict__ gstage,
                                              const unsigned* __restrict__ gcur,
                                              const unsigned* __restrict__ bktbase,
                                              int* __restrict__ rowptr, float* __restrict__ dinv,
                                              int* __restrict__ col, int N, int NBKT) {
    __shared__ unsigned image[BCAP];
    __shared__ unsigned cnt[256];
    __shared__ unsigned pref[256];
    __shared__ unsigned cur[256];
    int B = blockIdx.x, t = threadIdx.x;
    unsigned g = gcur[B];
    unsigned m = (g < BCAP) ? g : BCAP;
    unsigned base = bktbase[B];
    const unsigned* st = gstage + (size_t)B * BCAP;

    cnt[t] = 0u; cur[t] = 0u;
    __syncthreads();
    for (unsigned i = t; i < m; i += 256) atomicAdd(&cnt[(st[i] >> 16) & 255u], 1u);
    __syncthreads();
    pref[t] = cnt[t];
    __syncthreads();
    for (int off = 1; off < 256; off <<= 1) {
        unsigned add = (t >= off) ? pref[t - off] : 0u;
        __syncthreads();
        pref[t] += add;
        __syncthreads();
    }
    int d = B * 256 + t;
    if (d < N) {
        rowptr[d] = (int)(base + pref[t] - cnt[t]);
        dinv[d] = rsqrtf((float)(cnt[t] + 1u));
    }
    if (B == NBKT - 1 && t == 0) rowptr[N] = (int)(base + m);
    for (unsigned i = t; i < m; i += 256) {
        unsigned v = st[i];
        unsigned dl = (v >> 16) & 255u;
        unsigned pos = (pref[dl] - cnt[dl]) + atomicAdd(&cur[dl], 1u);
        image[pos] = v & 0xFFFFu;
    }
    __syncthreads();
    for (unsigned i = t; i < m; i += 256) col[base + i] = (int)image[i];
}

// ---------------- xhS = fp16(dinv*x) in 4 column slices [4][N][32]; x16 = fp16(x) ----------------
__global__ __launch_bounds__(256) void xhk(const float* __restrict__ x, const float* __restrict__ dinv,
                                           __half* __restrict__ xhS, __half* __restrict__ x16, int N) {
    int i = blockIdx.x * 256 + threadIdx.x;   // one half2 per thread
    if (i >= N * 64) return;
    int node = i >> 6, fp = (i & 63) * 2;
    float w = dinv[node];
    float2 f = *(const float2*)&x[(size_t)node * C + fp];
    __half2 h = __floats2half2_rn(f.x * w, f.y * w);
    __half2 hx = __floats2half2_rn(f.x, f.y);
    int s = fp >> 5, off = fp & 31;
    *(unsigned*)&xhS[((size_t)s * N + node) * 32 + off] = *(unsigned*)&h;
    *(unsigned*)&x16[(size_t)node * C + fp] = *(unsigned*)&hx;
}

// ---------------- CSR gather, 4 column-sliced passes (slice = 3.2MB, fits XCD L2) -------------
// blockIdx.y = pass p. Wave per node; 8 neighbor-groups x 8 feature-lanes:
// lane = g*8+q handles neighbors j==g (mod 8), features q*4..q*4+3 of the 32-col slice.
__global__ __launch_bounds__(256) void gatherk(const int* __restrict__ col,
                                               const int* __restrict__ rowptr,
                                               const __half* __restrict__ xhS,
                                               const float* __restrict__ dinv,
                                               __half* __restrict__ gg, int N) {
    __shared__ int snb[4][64];
    int t = threadIdx.x;
    int wid = t >> 6, lane = t & 63;
    int d = blockIdx.x * 4 + wid;
    int p = blockIdx.y;
    if (d >= N) return;
    const __half* xs = xhS + (size_t)p * N * 32;
    int beg = rowptr[d], end = rowptr[d + 1];
    int g = lane >> 3, q = lane & 7;
    int f = q * 4;

    float a0 = 0.f, a1 = 0.f, a2 = 0.f, a3 = 0.f;

    for (int c = beg; c < end; c += 64) {
        if (c + lane < end) snb[wid][lane] = col[c + lane];
        int n = end - c; if (n > 64) n = 64;
        for (int j = g; j < n; j += 8) {
            float4 v = h4_to_f4(*(const uint2*)&xs[(size_t)snb[wid][j] * 32 + f]);
            a0 += v.x; a1 += v.y; a2 += v.z; a3 += v.w;
        }
    }
    // reduce across the 8 neighbor groups
    a0 += __shfl_xor(a0, 8, 64);  a0 += __shfl_xor(a0, 16, 64);  a0 += __shfl_xor(a0, 32, 64);
    a1 += __shfl_xor(a1, 8, 64);  a1 += __shfl_xor(a1, 16, 64);  a1 += __shfl_xor(a1, 32, 64);
    a2 += __shfl_xor(a2, 8, 64);  a2 += __shfl_xor(a2, 16, 64);  a2 += __shfl_xor(a2, 32, 64);
    a3 += __shfl_xor(a3, 8, 64);  a3 += __shfl_xor(a3, 16, 64);  a3 += __shfl_xor(a3, 32, 64);

    if (g == 0) {
        float4 s4 = h4_to_f4(*(const uint2*)&xs[(size_t)d * 32 + f]);
        float dv = dinv[d];
        __half2 h0 = __floats2half2_rn((a0 + s4.x) * dv, (a1 + s4.y) * dv);
        __half2 h1 = __floats2half2_rn((a2 + s4.z) * dv, (a3 + s4.w) * dv);
        uint2 u; u.x = *(unsigned*)&h0; u.y = *(unsigned*)&h1;
        *(uint2*)&gg[(size_t)d * C + p * 32 + f] = u;
    }
}

// ---------------- merged GCN GEMM, nc split across waves, x16 register-prefetched -------------
__global__ __launch_bounds__(256) void gemm2k(const __half* __restrict__ gg,
                                              const __half* __restrict__ wt,     // [2][128][128]
                                              const __half* __restrict__ a1wt,   // [32][128]
                                              const float* __restrict__ ab, const float* __restrict__ cb,
                                              const __half* __restrict__ x16,
                                              const float* __restrict__ a1b,
                                              const float* __restrict__ a2W, const float* __restrict__ a2b,
                                              const float* __restrict__ a3W, const float* __restrict__ a3b,
                                              float* __restrict__ scratch,
                                              float* __restrict__ out, float* __restrict__ pSum, int N) {
    __shared__ char As[16384];    // gg tile: 64 rows x 128 k fp16, XOR swizzle
    __shared__ char Act[16384];   // activations, same layout
    __shared__ char Aux[8448];    // w2t [32][40] | h1b [64][40] | w3s [32][2] | scol [128]
    _Float16* w2t = (_Float16*)Aux;            // 2560 B
    _Float16* h1b = (_Float16*)(Aux + 2560);   // 5120 B
    float* w3s    = (float*)(Aux + 7680);      // 256 B
    float* scol   = (float*)(Aux + 7936);      // 512 B

    const int row0 = blockIdx.x * 64;
    const int t = threadIdx.x;
    const int wv = t >> 6, l = t & 63;
    const int lm = l & 15, lk = l >> 4;
    const int koffB = lk * 16;
    const int koffH = lk * 8;

    // ---- prefetch x16 residuals for this thread's 4 rows x 2 ncs (overlaps staging) ----
    uint2 xpre[4][2];
#pragma unroll
    for (int rg = 0; rg < 4; ++rg) {
        int grow = row0 + rg * 16 + lm;
#pragma unroll
        for (int nc2 = 0; nc2 < 2; ++nc2) {
            int nc = wv * 2 + nc2;
            xpre[rg][nc2] = (grow < N) ? *(const uint2*)&x16[(size_t)grow * C + nc * 16 + lk * 4]
                                       : make_uint2(0u, 0u);
        }
    }

    // stage A (64 rows of gg)
#pragma unroll
    for (int i = 0; i < 4; ++i) {
        int c = t + i * 256;
        int row = c >> 4, cb16 = (c & 15) * 16;
        int grow = row0 + row;
        uint4 u = make_uint4(0u, 0u, 0u, 0u);
        if (grow < N) u = *(const uint4*)&gg[(size_t)grow * C + (c & 15) * 8];
        *(uint4*)(As + row * 256 + (cb16 ^ ((row & 7) << 4))) = u;
    }
#pragma unroll
    for (int i = 0; i < 4; ++i) {
        int idx = t + i * 256;
        int k = idx >> 5, n = idx & 31;
        w2t[n * 40 + k] = (_Float16)a2W[idx];
    }
    if (t < 64) w3s[t] = a3W[t];
    __syncthreads();

    const __half* WA = wt;
    const __half* WC = wt + 16384;

#pragma unroll
    for (int nc2 = 0; nc2 < 2; ++nc2) {
        const int nc = wv * 2 + nc2;
        const __half* wpA = WA + (nc * 16 + lm) * 128;
        const __half* wpC = WC + (nc * 16 + lm) * 128;
        half8x bfA[4], bfC[4];
#pragma unroll
        for (int kc = 0; kc < 4; ++kc) {
            bfA[kc] = *(const half8x*)(wpA + kc * 32 + koffH);
            bfC[kc] = *(const half8x*)(wpC + kc * 32 + koffH);
        }
        float4 bvA = *(const float4*)&ab[nc * 16 + lk * 4];
        float4 bvC = *(const float4*)&cb[nc * 16 + lk * 4];
        float v0 = 0.f, v1 = 0.f, v2 = 0.f, v3 = 0.f;

#pragma unroll
        for (int rg = 0; rg < 4; ++rg) {
            int rowA = rg * 16 + lm;
            int grow = row0 + rowA;
            bool valid = grow < N;
            int sw = (rowA & 7) << 4;
            const char* rp = As + rowA * 256;
            f32x4 accA = {0.f, 0.f, 0.f, 0.f};
            f32x4 accC = {0.f, 0.f, 0.f, 0.f};
#pragma unroll
            for (int kc = 0; kc < 4; ++kc) {
                half8x afr = *(const half8x*)(rp + ((kc * 64 + koffB) ^ sw));
                accA = __builtin_amdgcn_mfma_f32_16x16x32_f16(bfA[kc], afr, accA, 0, 0, 0);
                accC = __builtin_amdgcn_mfma_f32_16x16x32_f16(bfC[kc], afr, accC, 0, 0, 0);
            }
            half4x xq = *(half4x*)&xpre[rg][nc2];
            half4x hv = { (_Float16)(valid ? fmaxf(accA[0] + bvA.x, 0.f) + (float)xq[0] : 0.f),
                          (_Float16)(valid ? fmaxf(accA[1] + bvA.y, 0.f) + (float)xq[1] : 0.f),
                          (_Float16)(valid ? fmaxf(accA[2] + bvA.z, 0.f) + (float)xq[2] : 0.f),
                          (_Float16)(valid ? fmaxf(accA[3] + bvA.w, 0.f) + (float)xq[3] : 0.f) };
            *(half4x*)(Act + rowA * 256 + ((nc * 32 + lk * 8) ^ sw)) = hv;
            v0 += valid ? fmaxf(accC[0] + bvC.x, 0.f) + (float)xq[0] : 0.f;
            v1 += valid ? fmaxf(accC[1] + bvC.y, 0.f) + (float)xq[1] : 0.f;
            v2 += valid ? fmaxf(accC[2] + bvC.z, 0.f) + (float)xq[2] : 0.f;
            v3 += valid ? fmaxf(accC[3] + bvC.w, 0.f) + (float)xq[3] : 0.f;
        }
        v0 += __shfl_xor(v0, 1, 64); v0 += __shfl_xor(v0, 2, 64);
        v0 += __shfl_xor(v0, 4, 64); v0 += __shfl_xor(v0, 8, 64);
        v1 += __shfl_xor(v1, 1, 64); v1 += __shfl_xor(v1, 2, 64);
        v1 += __shfl_xor(v1, 4, 64); v1 += __shfl_xor(v1, 8, 64);
        v2 += __shfl_xor(v2, 1, 64); v2 += __shfl_xor(v2, 2, 64);
        v2 += __shfl_xor(v2, 4, 64); v2 += __shfl_xor(v2, 8, 64);
        v3 += __shfl_xor(v3, 1, 64); v3 += __shfl_xor(v3, 2, 64);
        v3 += __shfl_xor(v3, 4, 64); v3 += __shfl_xor(v3, 8, 64);
        if (lm == 0)
            *(float4*)&scol[nc * 16 + lk * 4] = make_float4(v0, v1, v2, v3);
    }
    __syncthreads();

    if (t < 128)
        scratch[(size_t)blockIdx.x * 128 + t] = scol[t];

    // ---- actor MLP ----
    const int rowM = wv * 16 + lm;
    const int growM = row0 + rowM;
    const bool validM = growM < N;
    const int swM = (rowM & 7) << 4;

    half8x a1f[4];
    {
        const char* rp = Act + rowM * 256;
#pragma unroll
        for (int kc = 0; kc < 4; ++kc)
            a1f[kc] = *(const half8x*)(rp + ((kc * 64 + koffB) ^ swM));
    }
#pragma unroll
    for (int ct = 0; ct < 2; ++ct) {
        const __half* ap = a1wt + (ct * 16 + lm) * 128;
        f32x4 acc1 = {0.f, 0.f, 0.f, 0.f};
#pragma unroll
        for (int kc = 0; kc < 4; ++kc) {
            half8x bq = *(const half8x*)(ap + kc * 32 + koffH);
            acc1 = __builtin_amdgcn_mfma_f32_16x16x32_f16(bq, a1f[kc], acc1, 0, 0, 0);
        }
        float4 b1v = *(const float4*)&a1b[ct * 16 + lk * 4];
        half4x h = { (_Float16)fmaxf(acc1[0] + b1v.x, 0.f),
                     (_Float16)fmaxf(acc1[1] + b1v.y, 0.f),
                     (_Float16)fmaxf(acc1[2] + b1v.z, 0.f),
                     (_Float16)fmaxf(acc1[3] + b1v.w, 0.f) };
        *(half4x*)((char*)h1b + rowM * 80 + ct * 32 + lk * 8) = h;
    }

    half4x alo = *(const half4x*)((char*)h1b + rowM * 80 + lk * 16);
    half4x ahi = *(const half4x*)((char*)h1b + rowM * 80 + lk * 16 + 8);
    half8x a2f = __builtin_shufflevector(alo, ahi, 0, 1, 2, 3, 4, 5, 6, 7);
    float p0 = 0.f, p1 = 0.f;
#pragma unroll
    for (int ct = 0; ct < 2; ++ct) {
        half4x blo = *(const half4x*)((char*)w2t + (ct * 16 + lm) * 80 + lk * 16);
        half4x bhi = *(const half4x*)((char*)w2t + (ct * 16 + lm) * 80 + lk * 16 + 8);
        half8x b2f = __builtin_shufflevector(blo, bhi, 0, 1, 2, 3, 4, 5, 6, 7);
        f32x4 acc2 = {0.f, 0.f, 0.f, 0.f};
        acc2 = __builtin_amdgcn_mfma_f32_16x16x32_f16(b2f, a2f, acc2, 0, 0, 0);
        float4 b2v = *(const float4*)&a2b[ct * 16 + lk * 4];
#pragma unroll
        for (int j = 0; j < 4; ++j) {
            int f = ct * 16 + lk * 4 + j;
            float h2v = fmaxf(acc2[j] + (&b2v.x)[j], 0.f);
            float2 w3 = *(const float2*)&w3s[f * 2];
            p0 += h2v * w3.x;
            p1 += h2v * w3.y;
        }
    }
    p0 += __shfl_xor(p0, 16, 64); p0 += __shfl_xor(p0, 32, 64);
    p1 += __shfl_xor(p1, 16, 64); p1 += __shfl_xor(p1, 32, 64);
    float wave_psum = 0.f;
    if (lk == 0 && validM) {
        float s0 = softplusf(p0 + a3b[0]);
        float s1 = softplusf(p1 + a3b[1]);
        out[growM] = s0 + 1e-20f;
        out[(size_t)N + 2 + growM] = s1;
        wave_psum = s1;
    }
    wave_psum += __shfl_xor(wave_psum, 1, 64);
    wave_psum += __shfl_xor(wave_psum, 2, 64);
    wave_psum += __shfl_xor(wave_psum, 4, 64);
    wave_psum += __shfl_xor(wave_psum, 8, 64);
    wave_psum += __shfl_xor(wave_psum, 16, 64);
    wave_psum += __shfl_xor(wave_psum, 32, 64);
    if (l == 0) atomicAdd(pSum, wave_psum);
}

// ---------------- reduce scratch -> colsum ----------------
__global__ __launch_bounds__(128) void csredk(const float* __restrict__ scratch, float* __restrict__ colsum, int nblk) {
    int t = threadIdx.x;
    float s = 0.f;
    for (int b = blockIdx.x; b < nblk; b += gridDim.x)
        s += scratch[(size_t)b * 128 + t];
    atomicAdd(&colsum[t], s);
}

// ---------------- critic head ----------------
__global__ void critick(const float* __restrict__ colsum,
                        const float* __restrict__ c1W, const float* __restrict__ c1b,
                        const float* __restrict__ c2W, const float* __restrict__ c2b,
                        const float* __restrict__ c3W, const float* __restrict__ c3b,
                        float* __restrict__ out, int N) {
    __shared__ float s1[32], s2[32];
    int t = threadIdx.x;
    if (t < 32) {
        float acc = c1b[t];
        for (int k = 0; k < 128; ++k) acc += colsum[k] * c1W[k * 32 + t];
        s1[t] = fmaxf(acc, 0.f);
    }
    __syncthreads();
    if (t < 32) {
        float acc = c2b[t];
        for (int k = 0; k < 32; ++k) acc += s1[k] * c2W[k * 32 + t];
        s2[t] = fmaxf(acc, 0.f);
    }
    __syncthreads();
    if (t < 2) {
        float acc = c3b[t];
        for (int k = 0; k < 32; ++k) acc += s2[k] * c3W[k * 2 + t];
        out[(size_t)N + t] = acc;
    }
}

// ---------------- normalize probs ----------------
__global__ __launch_bounds__(256) void normk(float* __restrict__ out, const float* __restrict__ pSum, int N) {
    int i = blockIdx.x * 256 + threadIdx.x;
    if (i < N) out[(size_t)N + 2 + i] /= pSum[0];
}

extern "C" void kernel_launch(void* const* d_in, const int* in_sizes, int n_in,
                              void* d_out, int out_size, void* d_ws, size_t ws_size,
                              hipStream_t stream) {
    const float* x   = (const float*)d_in[0];
    const int* ei    = (const int*)d_in[1];
    const float* aW  = (const float*)d_in[2];
    const float* ab  = (const float*)d_in[3];
    const float* a1W = (const float*)d_in[4];
    const float* a1b = (const float*)d_in[5];
    const float* a2W = (const float*)d_in[6];
    const float* a2b = (const float*)d_in[7];
    const float* a3W = (const float*)d_in[8];
    const float* a3b = (const float*)d_in[9];
    const float* cW  = (const float*)d_in[10];
    const float* cb  = (const float*)d_in[11];
    const float* c1W = (const float*)d_in[12];
    const float* c1b = (const float*)d_in[13];
    const float* c2W = (const float*)d_in[14];
    const float* c2b = (const float*)d_in[15];
    const float* c3W = (const float*)d_in[16];
    const float* c3b = (const float*)d_in[17];

    const int N = in_sizes[0] / C;
    const int E = in_sizes[1] / 2;
    const int NBKT = (N + 255) / 256;          // 256-node buckets (N < 65536)
    const int nblk64 = (N + 63) / 64;
    float* out = (float*)d_out;

    char* ws = (char*)d_ws;
    size_t off = 0;
    auto alloc = [&](size_t bytes) {
        size_t o = off;
        off = (off + bytes + 255) & ~(size_t)255;
        return (void*)(ws + o);
    };
    unsigned* gcur    = (unsigned*)alloc(256 * 4);
    unsigned* bktbase = (unsigned*)alloc(256 * 4);
    unsigned* gstage  = (unsigned*)alloc((size_t)NBKT * BCAP * 4);
    int* rowptr       = (int*)alloc((size_t)(N + 1) * 4);
    float* dinv       = (float*)alloc((size_t)N * 4);
    int* colidx       = (int*)alloc((size_t)E * 4);
    __half* xhS       = (__half*)alloc((size_t)N * C * 2);   // [4][N][32] slices
    __half* x16       = (__half*)alloc((size_t)N * C * 2);
    __half* gg        = (__half*)alloc((size_t)N * C * 2);
    __half* wt        = (__half*)alloc(2 * 16384 * 2);
    __half* a1wt      = (__half*)alloc(4096 * 2);
    float* scratch    = (float*)alloc((size_t)nblk64 * 128 * 4);
    float* colsum     = (float*)alloc(128 * 4);
    float* pSum       = (float*)alloc(4);

    initk<<<1, 256, 0, stream>>>(gcur, colsum, pSum);
    wtk<<<144, 256, 0, stream>>>(aW, cW, a1W, wt, a1wt);
    bink<<<256, 256, 0, stream>>>(ei, gcur, gstage, E, NBKT);
    bktscank<<<1, 256, 0, stream>>>(gcur, bktbase, NBKT);
    placek<<<NBKT, 256, 0, stream>>>(gstage, gcur, bktbase, rowptr, dinv, colidx, N, NBKT);
    xhk<<<(N * 64 + 255) / 256, 256, 0, stream>>>(x, dinv, xhS, x16, N);
    gatherk<<<dim3((N + 3) / 4, 4), 256, 0, stream>>>(colidx, rowptr, xhS, dinv, gg, N);
    gemm2k<<<nblk64, 256, 0, stream>>>(gg, wt, a1wt, ab, cb, x16,
                                       a1b, a2W, a2b, a3W, a3b,
                                       scratch, out, pSum, N);
    csredk<<<8, 128, 0, stream>>>(scratch, colsum, nblk64);
    critick<<<1, 64, 0, stream>>>(colsum, c1W, c1b, c2W, c2b, c3W, c3b, out, N);
    normk<<<(N + 255) / 256, 256, 0, stream>>>(out, pSum, N);
}

// Round 17
// 210.790 us; speedup vs baseline: 1.1731x; 1.1731x over previous
//
#include <hip/hip_runtime.h>
#include <hip/hip_bf16.h>
#include <hip/hip_fp16.h>
#include <math.h>

#define C 128
#define BCAP 12288   // per-bucket staging capacity (expected ~8.2K edges/bucket)

using half8x = __attribute__((ext_vector_type(8))) _Float16;
using half4x = __attribute__((ext_vector_type(4))) _Float16;
using f32x4  = __attribute__((ext_vector_type(4))) float;

__device__ inline float4 h4_to_f4(uint2 u) {
    __half2 p0 = *(__half2*)&u.x;
    __half2 p1 = *(__half2*)&u.y;
    float2 f0 = __half22float2(p0), f1 = __half22float2(p1);
    return make_float4(f0.x, f0.y, f1.x, f1.y);
}

__device__ inline float softplusf(float v) {
    return (v > 20.f) ? v : log1pf(expf(v));
}

// ---------------- transpose weights to fp16 once + init (block 0) ----------------
__global__ __launch_bounds__(256) void wtk(const float* __restrict__ aW, const float* __restrict__ cW,
                                           const float* __restrict__ a1W,
                                           __half* __restrict__ wt, __half* __restrict__ a1wt,
                                           unsigned* gcur, float* colsum, float* pSum) {
    int t = threadIdx.x;
    if (blockIdx.x == 0) {
        gcur[t] = 0u;
        if (t < 128) colsum[t] = 0.f;
        if (t == 128) pSum[0] = 0.f;
    }
    int idx = blockIdx.x * 256 + t;
    if (idx < 32768) {
        int y = idx >> 14, r = idx & 16383;
        int k = r >> 7, n = r & 127;
        const float* W = y ? cW : aW;
        wt[((size_t)y << 14) + n * 128 + k] = __float2half(W[k * 128 + n]);
    } else if (idx < 36864) {
        int r = idx - 32768;
        int k = r >> 5, n = r & 31;
        a1wt[n * 128 + k] = __float2half(a1W[k * 32 + n]);
    }
}

// ---------------- bucket-bin edges (counting sort level 1) ----------------
__global__ __launch_bounds__(256) void bink(const int* __restrict__ ei,
                                            unsigned* __restrict__ gcur,
                                            unsigned* __restrict__ gstage,
                                            int E, int NBKT) {
    __shared__ unsigned raw[6400];
    __shared__ unsigned image[6400];
    __shared__ unsigned cnt[256];
    __shared__ unsigned pref[256];
    __shared__ unsigned cur[256];
    __shared__ unsigned gb[256];
    int t = threadIdx.x, b = blockIdx.x;
    int elo = (int)((long long)b * E / 256);
    int ehi = (int)((long long)(b + 1) * E / 256);
    int n = ehi - elo;

    for (int i = t; i < n; i += 256) {
        int d = __builtin_nontemporal_load(ei + E + elo + i);
        int s = __builtin_nontemporal_load(ei + elo + i);
        raw[i] = (unsigned)s | ((unsigned)(d & 255) << 16) | ((unsigned)(d >> 8) << 24);
    }
    cnt[t] = 0u; cur[t] = 0u;
    __syncthreads();
    for (int i = t; i < n; i += 256) atomicAdd(&cnt[raw[i] >> 24], 1u);
    __syncthreads();
    pref[t] = cnt[t];
    __syncthreads();
    for (int off = 1; off < 256; off <<= 1) {
        unsigned add = (t >= off) ? pref[t - off] : 0u;
        __syncthreads();
        pref[t] += add;
        __syncthreads();
    }
    gb[t] = (t < NBKT && cnt[t]) ? atomicAdd(&gcur[t], cnt[t]) : 0u;
    __syncthreads();
    for (int i = t; i < n; i += 256) {
        unsigned v = raw[i];
        unsigned B = v >> 24;
        unsigned pos = (pref[B] - cnt[B]) + atomicAdd(&cur[B], 1u);
        image[pos] = v & 0xFFFFFFu;
    }
    __syncthreads();
    int wv = t >> 6, lane = t & 63;
    for (int B = wv; B < NBKT; B += 4) {
        unsigned c = cnt[B];
        if (!c) continue;
        unsigned eb = pref[B] - c;
        unsigned gbase = gb[B];
        unsigned c2 = (gbase < BCAP) ? ((c < BCAP - gbase) ? c : BCAP - gbase) : 0u;
        for (unsigned i = lane; i < c2; i += 64)
            gstage[(size_t)B * BCAP + gbase + i] = image[eb + i];
    }
}

// ---------------- place (counting sort level 2) + in-block bucket scan ----------------
__global__ __launch_bounds__(256) void placek(const unsigned* __restrict__ gstage,
                                              const unsigned* __restrict__ gcur,
                                              int* __restrict__ rowptr, float* __restrict__ dinv,
                                              int* __restrict__ col, int N, int NBKT) {
    __shared__ unsigned image[BCAP];
    __shared__ unsigned cnt[256];
    __shared__ unsigned pref[256];
    __shared__ unsigned cur[256];
    __shared__ unsigned sbase[256];
    int B = blockIdx.x, t = threadIdx.x;

    // redundant per-block scan of clamped bucket totals (replaces bktscank)
    unsigned gv = (t < NBKT) ? gcur[t] : 0u;
    unsigned val = (gv < BCAP) ? gv : BCAP;
    sbase[t] = val;
    __syncthreads();
    for (int off = 1; off < 256; off <<= 1) {
        unsigned add = (t >= off) ? sbase[t - off] : 0u;
        __syncthreads();
        sbase[t] += add;
        __syncthreads();
    }
    unsigned gB = gcur[B];
    unsigned m = (gB < BCAP) ? gB : BCAP;
    unsigned base = sbase[B] - m;   // exclusive prefix for bucket B
    const unsigned* st = gstage + (size_t)B * BCAP;

    cnt[t] = 0u; cur[t] = 0u;
    __syncthreads();
    for (unsigned i = t; i < m; i += 256) atomicAdd(&cnt[(st[i] >> 16) & 255u], 1u);
    __syncthreads();
    pref[t] = cnt[t];
    __syncthreads();
    for (int off = 1; off < 256; off <<= 1) {
        unsigned add = (t >= off) ? pref[t - off] : 0u;
        __syncthreads();
        pref[t] += add;
        __syncthreads();
    }
    int d = B * 256 + t;
    if (d < N) {
        rowptr[d] = (int)(base + pref[t] - cnt[t]);
        dinv[d] = rsqrtf((float)(cnt[t] + 1u));
    }
    if (B == NBKT - 1 && t == 0) rowptr[N] = (int)(base + m);
    for (unsigned i = t; i < m; i += 256) {
        unsigned v = st[i];
        unsigned dl = (v >> 16) & 255u;
        unsigned pos = (pref[dl] - cnt[dl]) + atomicAdd(&cur[dl], 1u);
        image[pos] = v & 0xFFFFu;
    }
    __syncthreads();
    for (unsigned i = t; i < m; i += 256) col[base + i] = (int)image[i];
}

// ---------------- xh = fp16(dinv*x) [N][128]; x16 = fp16(x) ----------------
__global__ __launch_bounds__(256) void xhk(const float* __restrict__ x, const float* __restrict__ dinv,
                                           __half* __restrict__ xh, __half* __restrict__ x16, int N) {
    int i = blockIdx.x * 256 + threadIdx.x;   // one half2 per thread
    if (i >= N * 64) return;
    int node = i >> 6, fp = (i & 63) * 2;
    float w = dinv[node];
    float2 f = *(const float2*)&x[(size_t)node * C + fp];
    __half2 h = __floats2half2_rn(f.x * w, f.y * w);
    __half2 hx = __floats2half2_rn(f.x, f.y);
    *(unsigned*)&xh[(size_t)node * C + fp] = *(unsigned*)&h;
    *(unsigned*)&x16[(size_t)node * C + fp] = *(unsigned*)&hx;
}

// ---------------- CSR gather in x-space (wave per node, 2-neighbor parity) ----------------
__global__ __launch_bounds__(256) void gatherk(const int* __restrict__ col,
                                               const int* __restrict__ rowptr,
                                               const __half* __restrict__ xh,
                                               const float* __restrict__ dinv,
                                               __half* __restrict__ gg, int N) {
    __shared__ int snb[4][64];
    int t = threadIdx.x;
    int wid = t >> 6, lane = t & 63;
    int d = blockIdx.x * 4 + wid;
    if (d >= N) return;
    int beg = rowptr[d], end = rowptr[d + 1];
    int half = lane >> 5, sub = lane & 31;
    int f = sub * 4;

    float a0 = 0.f, a1 = 0.f, a2 = 0.f, a3 = 0.f;

    for (int c = beg; c < end; c += 64) {
        if (c + lane < end) snb[wid][lane] = __builtin_nontemporal_load(col + c + lane);
        int n = end - c; if (n > 64) n = 64;
        int j = 0;
        for (; j + 3 < n; j += 4) {
            size_t i0 = (size_t)snb[wid][j + half] * C + f;
            size_t i1 = (size_t)snb[wid][j + 2 + half] * C + f;
            float4 v0 = h4_to_f4(*(const uint2*)&xh[i0]);
            float4 v1 = h4_to_f4(*(const uint2*)&xh[i1]);
            a0 += v0.x + v1.x;
            a1 += v0.y + v1.y;
            a2 += v0.z + v1.z;
            a3 += v0.w + v1.w;
        }
        for (; j < n; j += 2) {
            if (j + half < n) {
                float4 v = h4_to_f4(*(const uint2*)&xh[(size_t)snb[wid][j + half] * C + f]);
                a0 += v.x; a1 += v.y; a2 += v.z; a3 += v.w;
            }
        }
    }
    a0 += __shfl_xor(a0, 32, 64);
    a1 += __shfl_xor(a1, 32, 64);
    a2 += __shfl_xor(a2, 32, 64);
    a3 += __shfl_xor(a3, 32, 64);

    if (half == 0) {
        float4 s4 = h4_to_f4(*(const uint2*)&xh[(size_t)d * C + f]);
        float dv = dinv[d];
        __half2 h0 = __floats2half2_rn((a0 + s4.x) * dv, (a1 + s4.y) * dv);
        __half2 h1 = __floats2half2_rn((a2 + s4.z) * dv, (a3 + s4.w) * dv);
        uint2 u; u.x = *(unsigned*)&h0; u.y = *(unsigned*)&h1;
        *(uint2*)&gg[(size_t)d * C + f] = u;
    }
}

// ---------------- merged GCN GEMM, nc split across waves, x16 register-prefetched -------------
__global__ __launch_bounds__(256) void gemm2k(const __half* __restrict__ gg,
                                              const __half* __restrict__ wt,     // [2][128][128]
                                              const __half* __restrict__ a1wt,   // [32][128]
                                              const float* __restrict__ ab, const float* __restrict__ cb,
                                              const __half* __restrict__ x16,
                                              const float* __restrict__ a1b,
                                              const float* __restrict__ a2W, const float* __restrict__ a2b,
                                              const float* __restrict__ a3W, const float* __restrict__ a3b,
                                              float* __restrict__ scratch,
                                              float* __restrict__ out, float* __restrict__ pSum, int N) {
    __shared__ char As[16384];    // gg tile: 64 rows x 128 k fp16, XOR swizzle
    __shared__ char Act[16384];   // activations, same layout
    __shared__ char Aux[8448];    // w2t [32][40] | h1b [64][40] | w3s [32][2] | scol [128]
    _Float16* w2t = (_Float16*)Aux;            // 2560 B
    _Float16* h1b = (_Float16*)(Aux + 2560);   // 5120 B
    float* w3s    = (float*)(Aux + 7680);      // 256 B
    float* scol   = (float*)(Aux + 7936);      // 512 B

    const int row0 = blockIdx.x * 64;
    const int t = threadIdx.x;
    const int wv = t >> 6, l = t & 63;
    const int lm = l & 15, lk = l >> 4;
    const int koffB = lk * 16;
    const int koffH = lk * 8;

    // ---- prefetch x16 residuals (overlaps staging) ----
    uint2 xpre[4][2];
#pragma unroll
    for (int rg = 0; rg < 4; ++rg) {
        int grow = row0 + rg * 16 + lm;
#pragma unroll
        for (int nc2 = 0; nc2 < 2; ++nc2) {
            int nc = wv * 2 + nc2;
            xpre[rg][nc2] = (grow < N) ? *(const uint2*)&x16[(size_t)grow * C + nc * 16 + lk * 4]
                                       : make_uint2(0u, 0u);
        }
    }

    // stage A (64 rows of gg)
#pragma unroll
    for (int i = 0; i < 4; ++i) {
        int c = t + i * 256;
        int row = c >> 4, cb16 = (c & 15) * 16;
        int grow = row0 + row;
        uint4 u = make_uint4(0u, 0u, 0u, 0u);
        if (grow < N) u = *(const uint4*)&gg[(size_t)grow * C + (c & 15) * 8];
        *(uint4*)(As + row * 256 + (cb16 ^ ((row & 7) << 4))) = u;
    }
#pragma unroll
    for (int i = 0; i < 4; ++i) {
        int idx = t + i * 256;
        int k = idx >> 5, n = idx & 31;
        w2t[n * 40 + k] = (_Float16)a2W[idx];
    }
    if (t < 64) w3s[t] = a3W[t];
    __syncthreads();

    const __half* WA = wt;
    const __half* WC = wt + 16384;

#pragma unroll
    for (int nc2 = 0; nc2 < 2; ++nc2) {
        const int nc = wv * 2 + nc2;
        const __half* wpA = WA + (nc * 16 + lm) * 128;
        const __half* wpC = WC + (nc * 16 + lm) * 128;
        half8x bfA[4], bfC[4];
#pragma unroll
        for (int kc = 0; kc < 4; ++kc) {
            bfA[kc] = *(const half8x*)(wpA + kc * 32 + koffH);
            bfC[kc] = *(const half8x*)(wpC + kc * 32 + koffH);
        }
        float4 bvA = *(const float4*)&ab[nc * 16 + lk * 4];
        float4 bvC = *(const float4*)&cb[nc * 16 + lk * 4];
        float v0 = 0.f, v1 = 0.f, v2 = 0.f, v3 = 0.f;

#pragma unroll
        for (int rg = 0; rg < 4; ++rg) {
            int rowA = rg * 16 + lm;
            int grow = row0 + rowA;
            bool valid = grow < N;
            int sw = (rowA & 7) << 4;
            const char* rp = As + rowA * 256;
            f32x4 accA = {0.f, 0.f, 0.f, 0.f};
            f32x4 accC = {0.f, 0.f, 0.f, 0.f};
#pragma unroll
            for (int kc = 0; kc < 4; ++kc) {
                half8x afr = *(const half8x*)(rp + ((kc * 64 + koffB) ^ sw));
                accA = __builtin_amdgcn_mfma_f32_16x16x32_f16(bfA[kc], afr, accA, 0, 0, 0);
                accC = __builtin_amdgcn_mfma_f32_16x16x32_f16(bfC[kc], afr, accC, 0, 0, 0);
            }
            half4x xq = *(half4x*)&xpre[rg][nc2];
            half4x hv = { (_Float16)(valid ? fmaxf(accA[0] + bvA.x, 0.f) + (float)xq[0] : 0.f),
                          (_Float16)(valid ? fmaxf(accA[1] + bvA.y, 0.f) + (float)xq[1] : 0.f),
                          (_Float16)(valid ? fmaxf(accA[2] + bvA.z, 0.f) + (float)xq[2] : 0.f),
                          (_Float16)(valid ? fmaxf(accA[3] + bvA.w, 0.f) + (float)xq[3] : 0.f) };
            *(half4x*)(Act + rowA * 256 + ((nc * 32 + lk * 8) ^ sw)) = hv;
            v0 += valid ? fmaxf(accC[0] + bvC.x, 0.f) + (float)xq[0] : 0.f;
            v1 += valid ? fmaxf(accC[1] + bvC.y, 0.f) + (float)xq[1] : 0.f;
            v2 += valid ? fmaxf(accC[2] + bvC.z, 0.f) + (float)xq[2] : 0.f;
            v3 += valid ? fmaxf(accC[3] + bvC.w, 0.f) + (float)xq[3] : 0.f;
        }
        v0 += __shfl_xor(v0, 1, 64); v0 += __shfl_xor(v0, 2, 64);
        v0 += __shfl_xor(v0, 4, 64); v0 += __shfl_xor(v0, 8, 64);
        v1 += __shfl_xor(v1, 1, 64); v1 += __shfl_xor(v1, 2, 64);
        v1 += __shfl_xor(v1, 4, 64); v1 += __shfl_xor(v1, 8, 64);
        v2 += __shfl_xor(v2, 1, 64); v2 += __shfl_xor(v2, 2, 64);
        v2 += __shfl_xor(v2, 4, 64); v2 += __shfl_xor(v2, 8, 64);
        v3 += __shfl_xor(v3, 1, 64); v3 += __shfl_xor(v3, 2, 64);
        v3 += __shfl_xor(v3, 4, 64); v3 += __shfl_xor(v3, 8, 64);
        if (lm == 0)
            *(float4*)&scol[nc * 16 + lk * 4] = make_float4(v0, v1, v2, v3);
    }
    __syncthreads();

    if (t < 128)
        scratch[(size_t)blockIdx.x * 128 + t] = scol[t];

    // ---- actor MLP ----
    const int rowM = wv * 16 + lm;
    const int growM = row0 + rowM;
    const bool validM = growM < N;
    const int swM = (rowM & 7) << 4;

    half8x a1f[4];
    {
        const char* rp = Act + rowM * 256;
#pragma unroll
        for (int kc = 0; kc < 4; ++kc)
            a1f[kc] = *(const half8x*)(rp + ((kc * 64 + koffB) ^ swM));
    }
#pragma unroll
    for (int ct = 0; ct < 2; ++ct) {
        const __half* ap = a1wt + (ct * 16 + lm) * 128;
        f32x4 acc1 = {0.f, 0.f, 0.f, 0.f};
#pragma unroll
        for (int kc = 0; kc < 4; ++kc) {
            half8x bq = *(const half8x*)(ap + kc * 32 + koffH);
            acc1 = __builtin_amdgcn_mfma_f32_16x16x32_f16(bq, a1f[kc], acc1, 0, 0, 0);
        }
        float4 b1v = *(const float4*)&a1b[ct * 16 + lk * 4];
        half4x h = { (_Float16)fmaxf(acc1[0] + b1v.x, 0.f),
                     (_Float16)fmaxf(acc1[1] + b1v.y, 0.f),
                     (_Float16)fmaxf(acc1[2] + b1v.z, 0.f),
                     (_Float16)fmaxf(acc1[3] + b1v.w, 0.f) };
        *(half4x*)((char*)h1b + rowM * 80 + ct * 32 + lk * 8) = h;
    }

    half4x alo = *(const half4x*)((char*)h1b + rowM * 80 + lk * 16);
    half4x ahi = *(const half4x*)((char*)h1b + rowM * 80 + lk * 16 + 8);
    half8x a2f = __builtin_shufflevector(alo, ahi, 0, 1, 2, 3, 4, 5, 6, 7);
    float p0 = 0.f, p1 = 0.f;
#pragma unroll
    for (int ct = 0; ct < 2; ++ct) {
        half4x blo = *(const half4x*)((char*)w2t + (ct * 16 + lm) * 80 + lk * 16);
        half4x bhi = *(const half4x*)((char*)w2t + (ct * 16 + lm) * 80 + lk * 16 + 8);
        half8x b2f = __builtin_shufflevector(blo, bhi, 0, 1, 2, 3, 4, 5, 6, 7);
        f32x4 acc2 = {0.f, 0.f, 0.f, 0.f};
        acc2 = __builtin_amdgcn_mfma_f32_16x16x32_f16(b2f, a2f, acc2, 0, 0, 0);
        float4 b2v = *(const float4*)&a2b[ct * 16 + lk * 4];
#pragma unroll
        for (int j = 0; j < 4; ++j) {
            int f = ct * 16 + lk * 4 + j;
            float h2v = fmaxf(acc2[j] + (&b2v.x)[j], 0.f);
            float2 w3 = *(const float2*)&w3s[f * 2];
            p0 += h2v * w3.x;
            p1 += h2v * w3.y;
        }
    }
    p0 += __shfl_xor(p0, 16, 64); p0 += __shfl_xor(p0, 32, 64);
    p1 += __shfl_xor(p1, 16, 64); p1 += __shfl_xor(p1, 32, 64);
    float wave_psum = 0.f;
    if (lk == 0 && validM) {
        float s0 = softplusf(p0 + a3b[0]);
        float s1 = softplusf(p1 + a3b[1]);
        out[growM] = s0 + 1e-20f;
        out[(size_t)N + 2 + growM] = s1;
        wave_psum = s1;
    }
    wave_psum += __shfl_xor(wave_psum, 1, 64);
    wave_psum += __shfl_xor(wave_psum, 2, 64);
    wave_psum += __shfl_xor(wave_psum, 4, 64);
    wave_psum += __shfl_xor(wave_psum, 8, 64);
    wave_psum += __shfl_xor(wave_psum, 16, 64);
    wave_psum += __shfl_xor(wave_psum, 32, 64);
    if (l == 0) atomicAdd(pSum, wave_psum);
}

// ---------------- reduce scratch -> colsum ----------------
__global__ __launch_bounds__(128) void csredk(const float* __restrict__ scratch, float* __restrict__ colsum, int nblk) {
    int t = threadIdx.x;
    float s = 0.f;
    for (int b = blockIdx.x; b < nblk; b += gridDim.x)
        s += scratch[(size_t)b * 128 + t];
    atomicAdd(&colsum[t], s);
}

// ---------------- critic head ----------------
__global__ void critick(const float* __restrict__ colsum,
                        const float* __restrict__ c1W, const float* __restrict__ c1b,
                        const float* __restrict__ c2W, const float* __restrict__ c2b,
                        const float* __restrict__ c3W, const float* __restrict__ c3b,
                        float* __restrict__ out, int N) {
    __shared__ float s1[32], s2[32];
    int t = threadIdx.x;
    if (t < 32) {
        float acc = c1b[t];
        for (int k = 0; k < 128; ++k) acc += colsum[k] * c1W[k * 32 + t];
        s1[t] = fmaxf(acc, 0.f);
    }
    __syncthreads();
    if (t < 32) {
        float acc = c2b[t];
        for (int k = 0; k < 32; ++k) acc += s1[k] * c2W[k * 32 + t];
        s2[t] = fmaxf(acc, 0.f);
    }
    __syncthreads();
    if (t < 2) {
        float acc = c3b[t];
        for (int k = 0; k < 32; ++k) acc += s2[k] * c3W[k * 2 + t];
        out[(size_t)N + t] = acc;
    }
}

// ---------------- normalize probs ----------------
__global__ __launch_bounds__(256) void normk(float* __restrict__ out, const float* __restrict__ pSum, int N) {
    int i = blockIdx.x * 256 + threadIdx.x;
    if (i < N) out[(size_t)N + 2 + i] /= pSum[0];
}

extern "C" void kernel_launch(void* const* d_in, const int* in_sizes, int n_in,
                              void* d_out, int out_size, void* d_ws, size_t ws_size,
                              hipStream_t stream) {
    const float* x   = (const float*)d_in[0];
    const int* ei    = (const int*)d_in[1];
    const float* aW  = (const float*)d_in[2];
    const float* ab  = (const float*)d_in[3];
    const float* a1W = (const float*)d_in[4];
    const float* a1b = (const float*)d_in[5];
    const float* a2W = (const float*)d_in[6];
    const float* a2b = (const float*)d_in[7];
    const float* a3W = (const float*)d_in[8];
    const float* a3b = (const float*)d_in[9];
    const float* cW  = (const float*)d_in[10];
    const float* cb  = (const float*)d_in[11];
    const float* c1W = (const float*)d_in[12];
    const float* c1b = (const float*)d_in[13];
    const float* c2W = (const float*)d_in[14];
    const float* c2b = (const float*)d_in[15];
    const float* c3W = (const float*)d_in[16];
    const float* c3b = (const float*)d_in[17];

    const int N = in_sizes[0] / C;
    const int E = in_sizes[1] / 2;
    const int NBKT = (N + 255) / 256;          // 256-node buckets (N < 65536)
    const int nblk64 = (N + 63) / 64;
    float* out = (float*)d_out;

    char* ws = (char*)d_ws;
    size_t off = 0;
    auto alloc = [&](size_t bytes) {
        size_t o = off;
        off = (off + bytes + 255) & ~(size_t)255;
        return (void*)(ws + o);
    };
    unsigned* gcur    = (unsigned*)alloc(256 * 4);
    unsigned* gstage  = (unsigned*)alloc((size_t)NBKT * BCAP * 4);
    int* rowptr       = (int*)alloc((size_t)(N + 1) * 4);
    float* dinv       = (float*)alloc((size_t)N * 4);
    int* colidx       = (int*)alloc((size_t)E * 4);
    __half* xh        = (__half*)alloc((size_t)N * C * 2);
    __half* x16       = (__half*)alloc((size_t)N * C * 2);
    __half* gg        = (__half*)alloc((size_t)N * C * 2);
    __half* wt        = (__half*)alloc(2 * 16384 * 2);
    __half* a1wt      = (__half*)alloc(4096 * 2);
    float* scratch    = (float*)alloc((size_t)nblk64 * 128 * 4);
    float* colsum     = (float*)alloc(128 * 4);
    float* pSum       = (float*)alloc(4);

    wtk<<<144, 256, 0, stream>>>(aW, cW, a1W, wt, a1wt, gcur, colsum, pSum);
    bink<<<256, 256, 0, stream>>>(ei, gcur, gstage, E, NBKT);
    placek<<<NBKT, 256, 0, stream>>>(gstage, gcur, rowptr, dinv, colidx, N, NBKT);
    xhk<<<(N * 64 + 255) / 256, 256, 0, stream>>>(x, dinv, xh, x16, N);
    gatherk<<<(N + 3) / 4, 256, 0, stream>>>(colidx, rowptr, xh, dinv, gg, N);
    gemm2k<<<nblk64, 256, 0, stream>>>(gg, wt, a1wt, ab, cb, x16,
                                       a1b, a2W, a2b, a3W, a3b,
                                       scratch, out, pSum, N);
    csredk<<<8, 128, 0, stream>>>(scratch, colsum, nblk64);
    critick<<<1, 64, 0, stream>>>(colsum, c1W, c1b, c2W, c2b, c3W, c3b, out, N);
    normk<<<(N + 255) / 256, 256, 0, stream>>>(out, pSum, N);
}